// Round 6
// baseline (14.104 us; speedup 1.0000x reference)
//
#include <hip/hip_runtime.h>
#include <math.h>

// Graphene tight-binding band energies, closed form.
// Per k-point: p = a_lat*kx/2, b = a_lat*ky/(2*sqrt(3)).
//   f_re = -t * (2 cp cb + 2 cb^2 - 1)
//   f_im = -t * (2 sb (cp - cb))
//   e    = -2 t' * (2 cp^2 - 1 + 2 cp (4 cb^3 - 3 cb))
//   out  = (e -/+ sqrt(m^2 + f_re^2 + f_im^2)) * EV_TO_J   [ascending]
//
// Memory-bound (67 MB, caches flushed between replays by harness poison
// fills). Evidence so far: nt stores +1.8us (R3 vs R4); block-contiguous
// addressing +1.8us (R5 vs R3). Now at 5.1 TB/s effective (81% of copy
// ceiling). R5->R6 isolated change: nontemporal LOADS on the input stream
// (read-once, no reuse possible -> skip cache allocation).

typedef float f32x4 __attribute__((ext_vector_type(4)));

namespace {
constexpr double A_LAT_D = 2.46e-10;
constexpr float C_P  = (float)(A_LAT_D * 0.5);                           // a/2
constexpr float C_B  = (float)(A_LAT_D / (2.0 * 1.7320508075688772935)); // a/(2*sqrt3)
constexpr float T_EV  = 2.8f;
constexpr float TP_EV = 0.1f;
constexpr float M_EV  = 0.05f;
constexpr float EVJ   = 1.602176634e-19f;
}

__device__ __forceinline__ void graphene_point(float kx, float ky,
                                               float& lo, float& hi) {
    float p = kx * C_P;
    float b = ky * C_B;
    float cp = __cosf(p);
    float cb = __cosf(b);
    float sb = __sinf(b);
    float cb2 = cb * cb;
    float c3b = cb * (4.0f * cb2 - 3.0f);          // cos(3b)
    float fre = -T_EV * (2.0f * cp * cb + 2.0f * cb2 - 1.0f);
    float fim = -T_EV * (2.0f * sb * (cp - cb));
    float e   = -2.0f * TP_EV * (2.0f * cp * cp - 1.0f + 2.0f * cp * c3b);
    float r   = sqrtf(M_EV * M_EV + fre * fre + fim * fim);
    lo = (e - r) * EVJ;
    hi = (e + r) * EVJ;
}

__device__ __forceinline__ f32x4 graphene_pair(f32x4 kv) {
    f32x4 o;
    float ox, oy, oz, ow;
    graphene_point(kv.x, kv.y, ox, oy);
    graphene_point(kv.z, kv.w, oz, ow);
    o.x = ox; o.y = oy; o.z = oz; o.w = ow;
    return o;
}

__global__ __launch_bounds__(256)
void graphene_kernel(const f32x4* __restrict__ k4, f32x4* __restrict__ out4, int n4) {
    constexpr int ILP = 4;
    const int bsz  = 256;
    // each block owns a contiguous chunk of ILP*bsz f32x4 (16 KB in / 16 KB out)
    int base = blockIdx.x * (bsz * ILP) + threadIdx.x;

    if (base + 3 * bsz < n4) {
        f32x4 a = __builtin_nontemporal_load(&k4[base]);
        f32x4 b = __builtin_nontemporal_load(&k4[base + bsz]);
        f32x4 c = __builtin_nontemporal_load(&k4[base + 2 * bsz]);
        f32x4 d = __builtin_nontemporal_load(&k4[base + 3 * bsz]);
        f32x4 oa = graphene_pair(a);
        f32x4 ob = graphene_pair(b);
        f32x4 oc = graphene_pair(c);
        f32x4 od = graphene_pair(d);
        __builtin_nontemporal_store(oa, &out4[base]);
        __builtin_nontemporal_store(ob, &out4[base + bsz]);
        __builtin_nontemporal_store(oc, &out4[base + 2 * bsz]);
        __builtin_nontemporal_store(od, &out4[base + 3 * bsz]);
    } else {
        for (int j = 0; j < ILP; ++j) {
            int i = base + j * bsz;
            if (i < n4)
                __builtin_nontemporal_store(graphene_pair(__builtin_nontemporal_load(&k4[i])),
                                            &out4[i]);
        }
    }
}

extern "C" void kernel_launch(void* const* d_in, const int* in_sizes, int n_in,
                              void* d_out, int out_size, void* d_ws, size_t ws_size,
                              hipStream_t stream) {
    const f32x4* k4 = (const f32x4*)d_in[0];
    f32x4* out4 = (f32x4*)d_out;
    int n_floats = in_sizes[0];          // 2 * N_K
    int n4 = n_floats / 4;               // two k-points per f32x4
    constexpr int ILP = 4;
    int block = 256;
    int grid  = (n4 + block * ILP - 1) / (block * ILP);   // 2048 for N_K=4.2M
    graphene_kernel<<<grid, block, 0, stream>>>(k4, out4, n4);
}

// Round 7
// 13.530 us; speedup vs baseline: 1.0424x; 1.0424x over previous
//
#include <hip/hip_runtime.h>
#include <math.h>

// Graphene tight-binding band energies, closed form.
// Per k-point: p = a_lat*kx/2, b = a_lat*ky/(2*sqrt(3)).
//   f_re = -t * (2 cp cb + 2 cb^2 - 1)
//   f_im = -t * (2 sb (cp - cb))
//   e    = -2 t' * (2 cp^2 - 1 + 2 cp (4 cb^3 - 3 cb))
//   out  = (e -/+ sqrt(m^2 + f_re^2 + f_im^2)) * EV_TO_J   [ascending]
//
// Memory-bound (67 MB, caches flushed between replays by harness poison
// fills). Evidence ledger: nt stores +1.8us (R3/R4); block-contiguous
// +1.8us (R5/R3); nt loads ~-0.5us (R6, reverted).
// R5->R7 isolated change: ILP 4->8 (32 KB contiguous chunk per block,
// 1024 blocks) for longer sequential HBM runs + deeper per-thread MLP.

typedef float f32x4 __attribute__((ext_vector_type(4)));

namespace {
constexpr double A_LAT_D = 2.46e-10;
constexpr float C_P  = (float)(A_LAT_D * 0.5);                           // a/2
constexpr float C_B  = (float)(A_LAT_D / (2.0 * 1.7320508075688772935)); // a/(2*sqrt3)
constexpr float T_EV  = 2.8f;
constexpr float TP_EV = 0.1f;
constexpr float M_EV  = 0.05f;
constexpr float EVJ   = 1.602176634e-19f;
}

__device__ __forceinline__ void graphene_point(float kx, float ky,
                                               float& lo, float& hi) {
    float p = kx * C_P;
    float b = ky * C_B;
    float cp = __cosf(p);
    float cb = __cosf(b);
    float sb = __sinf(b);
    float cb2 = cb * cb;
    float c3b = cb * (4.0f * cb2 - 3.0f);          // cos(3b)
    float fre = -T_EV * (2.0f * cp * cb + 2.0f * cb2 - 1.0f);
    float fim = -T_EV * (2.0f * sb * (cp - cb));
    float e   = -2.0f * TP_EV * (2.0f * cp * cp - 1.0f + 2.0f * cp * c3b);
    float r   = sqrtf(M_EV * M_EV + fre * fre + fim * fim);
    lo = (e - r) * EVJ;
    hi = (e + r) * EVJ;
}

__device__ __forceinline__ f32x4 graphene_pair(f32x4 kv) {
    f32x4 o;
    float ox, oy, oz, ow;
    graphene_point(kv.x, kv.y, ox, oy);
    graphene_point(kv.z, kv.w, oz, ow);
    o.x = ox; o.y = oy; o.z = oz; o.w = ow;
    return o;
}

__global__ __launch_bounds__(256)
void graphene_kernel(const f32x4* __restrict__ k4, f32x4* __restrict__ out4, int n4) {
    constexpr int ILP = 8;
    const int bsz  = 256;
    // each block owns a contiguous chunk of ILP*bsz f32x4 (32 KB in / 32 KB out)
    int base = blockIdx.x * (bsz * ILP) + threadIdx.x;

    if (base + (ILP - 1) * bsz < n4) {
        f32x4 in[ILP];
#pragma unroll
        for (int j = 0; j < ILP; ++j) in[j] = k4[base + j * bsz];
        f32x4 o[ILP];
#pragma unroll
        for (int j = 0; j < ILP; ++j) o[j] = graphene_pair(in[j]);
#pragma unroll
        for (int j = 0; j < ILP; ++j)
            __builtin_nontemporal_store(o[j], &out4[base + j * bsz]);
    } else {
        for (int j = 0; j < ILP; ++j) {
            int i = base + j * bsz;
            if (i < n4)
                __builtin_nontemporal_store(graphene_pair(k4[i]), &out4[i]);
        }
    }
}

extern "C" void kernel_launch(void* const* d_in, const int* in_sizes, int n_in,
                              void* d_out, int out_size, void* d_ws, size_t ws_size,
                              hipStream_t stream) {
    const f32x4* k4 = (const f32x4*)d_in[0];
    f32x4* out4 = (f32x4*)d_out;
    int n_floats = in_sizes[0];          // 2 * N_K
    int n4 = n_floats / 4;               // two k-points per f32x4
    constexpr int ILP = 8;
    int block = 256;
    int grid  = (n4 + block * ILP - 1) / (block * ILP);   // 1024 for N_K=4.2M
    graphene_kernel<<<grid, block, 0, stream>>>(k4, out4, n4);
}

// Round 8
// 13.227 us; speedup vs baseline: 1.0662x; 1.0229x over previous
//
#include <hip/hip_runtime.h>
#include <math.h>

// Graphene tight-binding band energies, closed form. FINAL (ledger-best R5).
// Per k-point: p = a_lat*kx/2, b = a_lat*ky/(2*sqrt(3)).
//   f_re = -t * (2 cp cb + 2 cb^2 - 1)
//   f_im = -t * (2 sb (cp - cb))
//   e    = -2 t' * (2 cp^2 - 1 + 2 cp (4 cb^3 - 3 cb))
//   out  = (e -/+ sqrt(m^2 + f_re^2 + f_im^2)) * EV_TO_J   [ascending]
//
// Memory-bound: 67 MB irreducible traffic, caches flushed between replays
// by harness poison fills. Evidence ledger (within-session A/B):
//   nt stores          +1.8 us  (R3 vs R4)   — keep
//   block-contiguous   +1.8 us  (R5 vs R3)   — keep (16 KB chunk/block)
//   nt loads           -0.5 us  (R6)         — reverted
//   ILP 4->8           ~neutral (R7)         — reverted
// Final: 13.2 us = 5.1 TB/s = 81% of measured 6.29 TB/s copy ceiling.

typedef float f32x4 __attribute__((ext_vector_type(4)));

namespace {
constexpr double A_LAT_D = 2.46e-10;
constexpr float C_P  = (float)(A_LAT_D * 0.5);                           // a/2
constexpr float C_B  = (float)(A_LAT_D / (2.0 * 1.7320508075688772935)); // a/(2*sqrt3)
constexpr float T_EV  = 2.8f;
constexpr float TP_EV = 0.1f;
constexpr float M_EV  = 0.05f;
constexpr float EVJ   = 1.602176634e-19f;
}

__device__ __forceinline__ void graphene_point(float kx, float ky,
                                               float& lo, float& hi) {
    float p = kx * C_P;
    float b = ky * C_B;
    float cp = __cosf(p);
    float cb = __cosf(b);
    float sb = __sinf(b);
    float cb2 = cb * cb;
    float c3b = cb * (4.0f * cb2 - 3.0f);          // cos(3b)
    float fre = -T_EV * (2.0f * cp * cb + 2.0f * cb2 - 1.0f);
    float fim = -T_EV * (2.0f * sb * (cp - cb));
    float e   = -2.0f * TP_EV * (2.0f * cp * cp - 1.0f + 2.0f * cp * c3b);
    float r   = sqrtf(M_EV * M_EV + fre * fre + fim * fim);
    lo = (e - r) * EVJ;
    hi = (e + r) * EVJ;
}

__device__ __forceinline__ f32x4 graphene_pair(f32x4 kv) {
    f32x4 o;
    float ox, oy, oz, ow;
    graphene_point(kv.x, kv.y, ox, oy);
    graphene_point(kv.z, kv.w, oz, ow);
    o.x = ox; o.y = oy; o.z = oz; o.w = ow;
    return o;
}

__global__ __launch_bounds__(256)
void graphene_kernel(const f32x4* __restrict__ k4, f32x4* __restrict__ out4, int n4) {
    constexpr int ILP = 4;
    const int bsz  = 256;
    // each block owns a contiguous chunk of ILP*bsz f32x4 (16 KB in / 16 KB out)
    int base = blockIdx.x * (bsz * ILP) + threadIdx.x;

    if (base + 3 * bsz < n4) {
        f32x4 a = k4[base];
        f32x4 b = k4[base + bsz];
        f32x4 c = k4[base + 2 * bsz];
        f32x4 d = k4[base + 3 * bsz];
        f32x4 oa = graphene_pair(a);
        f32x4 ob = graphene_pair(b);
        f32x4 oc = graphene_pair(c);
        f32x4 od = graphene_pair(d);
        __builtin_nontemporal_store(oa, &out4[base]);
        __builtin_nontemporal_store(ob, &out4[base + bsz]);
        __builtin_nontemporal_store(oc, &out4[base + 2 * bsz]);
        __builtin_nontemporal_store(od, &out4[base + 3 * bsz]);
    } else {
        for (int j = 0; j < ILP; ++j) {
            int i = base + j * bsz;
            if (i < n4)
                __builtin_nontemporal_store(graphene_pair(k4[i]), &out4[i]);
        }
    }
}

extern "C" void kernel_launch(void* const* d_in, const int* in_sizes, int n_in,
                              void* d_out, int out_size, void* d_ws, size_t ws_size,
                              hipStream_t stream) {
    const f32x4* k4 = (const f32x4*)d_in[0];
    f32x4* out4 = (f32x4*)d_out;
    int n_floats = in_sizes[0];          // 2 * N_K
    int n4 = n_floats / 4;               // two k-points per f32x4
    constexpr int ILP = 4;
    int block = 256;
    int grid  = (n4 + block * ILP - 1) / (block * ILP);   // 2048 for N_K=4.2M
    graphene_kernel<<<grid, block, 0, stream>>>(k4, out4, n4);
}